// Round 10
// baseline (403.416 us; speedup 1.0000x reference)
//
#include <hip/hip_runtime.h>
#include <hip/hip_cooperative_groups.h>

namespace cg = cooperative_groups;

// ---------------------------------------------------------------------------
// self_transformer: q=xW1^T+b1, k=xW2^T+b2, v=xW3^T+b3,
//                   attn=softmax((k q^T)/sqrt(D)), out=attn@v
// N=4096, D=1024. All matmuls via mfma_f32_16x16x32_bf16, fp32 accum.
// R17 = R12 phases (best measured: 212.5us; rsum fusion of R13/R15/R16
//       REVERTED as net-negative) merged into ONE cooperative kernel with
//       5 grid.sync()s, eliminating 5 inter-kernel launch gaps (~61us of
//       the R12 window is outside all dispatches; the controllable part is
//       launch overhead ~3-10us per boundary).
//   Grid 256 blocks x 512 threads, 128KiB LDS -> exactly 1 block/CU on 256
//   CUs: co-residency for grid.sync guaranteed. No early returns anywhere
//   (phase work is guarded by ifs; every thread reaches every sync).
//   Phase block decode: prep/reduce grid-stride; qkv bid<192 -> (bid%12,
//   bid/12); transpose 4 64x64 tiles/block (2 concurrent x 2 iter);
//   E (bid&15, bid>>4); out (bid&3, (bid>>2)&15, bid>>6).
//   gemm body is VERBATIM R12: 8 phases / 2 K-tiles per iter, reads in
//   consume order (compiler per-use lgkmcnt), 1 stage (2 gld_lds) per
//   phase with rotation ph1:t+1.A1, ph2:t+2.A0, ph3:t+2.B0, ph4:t+2.B1,
//   ph5:t+2.A1, ph6:t+3.A0, ph7:t+3.B0, ph8:t+3.B1; vmcnt(6) only at
//   ph4/ph8; 1 barrier per phase; last iteration peeled (vmcnt(0) only
//   there); epilogue store order (mt,nt,r) — do NOT reorder (R13/R15:
//   (mt,r,nt) cost +7us on the out-gemm). LDS half [128 rows][8 granules
//   of 8 shorts], slot s of row r holds granule s^(r&7) -> 0 bank
//   conflicts (measured R7-R13).
// ---------------------------------------------------------------------------

typedef short bf16x8 __attribute__((ext_vector_type(8)));  // 8 bf16 = 4 VGPRs
typedef float f32x4  __attribute__((ext_vector_type(4)));

struct FalseT { static constexpr bool value = false; };
struct TrueT  { static constexpr bool value = true;  };

__device__ __forceinline__ short f2bf(float f) {
    unsigned u = __builtin_bit_cast(unsigned, f);
    u += 0x7FFFu + ((u >> 16) & 1u);   // round-to-nearest-even
    return (short)(u >> 16);
}
__device__ __forceinline__ float bf2f(short s) {
    return __builtin_bit_cast(float, (unsigned)((unsigned short)s) << 16);
}

__device__ __forceinline__ void gld_lds16(const short* g, short* l) {
    __builtin_amdgcn_global_load_lds(
        (const __attribute__((address_space(1))) void*)g,
        (__attribute__((address_space(3))) void*)l, 16, 0, 0);
}

#define WAITV(n) asm volatile("s_waitcnt vmcnt(" #n ")" ::: "memory")
#define BAR()    __builtin_amdgcn_s_barrier()

// ---------------------------------------------------------------------------
// 256x256 BT GEMM body (verbatim R12), K=1024 (8 full iterations).
// C[a][b] = scale * sum_i A[a*lda+i] * B[b*ldb+i]
// CMODE: 0 = bf16 + bias; 2 = bf16 exp(); 3 = bf16 (Cout pre-offset by z).
// ---------------------------------------------------------------------------
template<int CMODE>
__device__ void gemm_body(short (&As)[2][2][128 * 64],
                          short (&Bs)[2][2][128 * 64],
                          const short* __restrict__ A, int lda,
                          const short* __restrict__ B, int ldb,
                          const float* __restrict__ bias,
                          short* __restrict__ Cout, int ldc, float scale,
                          int K, int bx, int by, int koff)
{
    const int tid  = threadIdx.x;
    const int lane = tid & 63;
    const int wave = tid >> 6;           // 0..7
    const int wr   = wave >> 2;          // 0..1
    const int wc   = wave & 3;           // 0..3
    const int quad = lane >> 4;
    const int l16  = lane & 15;
    const size_t bm0 = (size_t)by * 256;
    const size_t bn0 = (size_t)bx * 256;

    f32x4 acc[8][4] = {};

    // staging decode: stage call writes 16 rows (wave*16..+15) of one half;
    // lane l -> row +8*i+(l>>3), LDS slot (l&7), global granule (l&7)^(l>>3)
    const int srow  = lane >> 3;
    const int sgran = (lane & 7) ^ srow;
    const short* Ag0 = A + (bm0 + wave * 16 + srow) * (size_t)lda + koff + sgran * 8;
    const short* Ag1 = Ag0 + (size_t)128 * lda;
    const short* Bg0 = B + (bn0 + wave * 16 + srow) * (size_t)ldb + koff + sgran * 8;
    const short* Bg1 = Bg0 + (size_t)128 * ldb;

    // fragment read offsets within a [128][64] half
    const int s0   = ((quad ^ (l16 & 7)) << 3);         // ks=0 slot
    const int s1   = (((4 + quad) ^ (l16 & 7)) << 3);   // ks=1 slot
    const int rdA0 = (wr * 64 + l16) * 64;
    const int rdB0 = (wc * 32 + l16) * 64;

    auto stage = [&](short* half, const short* g, int ld, int kt) {
#pragma unroll
        for (int i = 0; i < 2; ++i)
            gld_lds16(g + (size_t)(i * 8) * ld + kt,
                      half + (wave * 16 + i * 8) * 64);
    };

    bf16x8 af[4][2], bfr0[2][2], bfr1[2][2];

    auto ldA = [&](const short* Ah, int ks, int soff) {
#pragma unroll
        for (int m4 = 0; m4 < 4; ++m4)
            af[m4][ks] = *(const bf16x8*)(Ah + rdA0 + m4 * 1024 + soff);
    };
    auto ldB = [&](bf16x8 (&bx_)[2][2], const short* Bh, int ks, int soff) {
#pragma unroll
        for (int n2 = 0; n2 < 2; ++n2)
            bx_[n2][ks] = *(const bf16x8*)(Bh + rdB0 + n2 * 1024 + soff);
    };
    auto mmks = [&](int mq, int nq, bf16x8 (&bx_)[2][2], int ks) {
#pragma unroll
        for (int m4 = 0; m4 < 4; ++m4)
#pragma unroll
            for (int n2 = 0; n2 < 2; ++n2)
                acc[mq * 4 + m4][nq * 2 + n2] =
                    __builtin_amdgcn_mfma_f32_16x16x32_bf16(
                        af[m4][ks], bx_[n2][ks],
                        acc[mq * 4 + m4][nq * 2 + n2], 0, 0, 0);
    };

    // prologue: tile0 all 4 halves (8 loads, retired by vmcnt(6)), then
    // tile1 {A0,B0,B1} (6 loads, stay in flight). tile1.A1 staged at ph1.
    stage(&As[0][0][0], Ag0, lda, 0);
    stage(&Bs[0][0][0], Bg0, ldb, 0);
    stage(&Bs[0][1][0], Bg1, ldb, 0);
    stage(&As[0][1][0], Ag1, lda, 0);
    stage(&As[1][0][0], Ag0, lda, 64);
    stage(&Bs[1][0][0], Bg0, ldb, 64);
    stage(&Bs[1][1][0], Bg1, ldb, 64);
    WAITV(6);
    BAR();
    __builtin_amdgcn_sched_barrier(0);

    int kt = 0;
    auto iterbody = [&](auto LASTC) {
        constexpr bool LAST = decltype(LASTC)::value;
        // ---- ph1: tile t, quadrant (0,0) ----
        ldB(bfr0, &Bs[0][0][0], 0, s0);
        ldA(&As[0][0][0], 0, s0);
        ldB(bfr0, &Bs[0][0][0], 1, s1);
        ldA(&As[0][0][0], 1, s1);
        stage(&As[1][1][0], Ag1, lda, kt + 64);        // t+1.A1
        __builtin_amdgcn_s_setprio(1);
        mmks(0, 0, bfr0, 0); mmks(0, 0, bfr0, 1);
        __builtin_amdgcn_s_setprio(0);
        BAR();
        // ---- ph2: (0,1) ----
        ldB(bfr1, &Bs[0][1][0], 0, s0);
        ldB(bfr1, &Bs[0][1][0], 1, s1);
        if constexpr (!LAST) stage(&As[0][0][0], Ag0, lda, kt + 128);  // t+2.A0
        __builtin_amdgcn_s_setprio(1);
        mmks(0, 1, bfr1, 0); mmks(0, 1, bfr1, 1);
        __builtin_amdgcn_s_setprio(0);
        BAR();
        // ---- ph3: (1,1) ----
        ldA(&As[0][1][0], 0, s0);
        ldA(&As[0][1][0], 1, s1);
        if constexpr (!LAST) stage(&Bs[0][0][0], Bg0, ldb, kt + 128);  // t+2.B0
        __builtin_amdgcn_s_setprio(1);
        mmks(1, 1, bfr1, 0); mmks(1, 1, bfr1, 1);
        __builtin_amdgcn_s_setprio(0);
        BAR();
        // ---- ph4: (1,0) — register-only MFMA, publish tile t+1 ----
        if constexpr (!LAST) stage(&Bs[0][1][0], Bg1, ldb, kt + 128);  // t+2.B1
        __builtin_amdgcn_s_setprio(1);
        mmks(1, 0, bfr0, 0); mmks(1, 0, bfr0, 1);
        __builtin_amdgcn_s_setprio(0);
        if constexpr (LAST) { WAITV(0); } else { WAITV(6); }
        __builtin_amdgcn_sched_barrier(0);
        BAR();
        // ---- ph5: tile t+1, quadrant (0,0) ----
        ldB(bfr0, &Bs[1][0][0], 0, s0);
        ldA(&As[1][0][0], 0, s0);
        ldB(bfr0, &Bs[1][0][0], 1, s1);
        ldA(&As[1][0][0], 1, s1);
        if constexpr (!LAST) stage(&As[0][1][0], Ag1, lda, kt + 128);  // t+2.A1
        __builtin_amdgcn_s_setprio(1);
        mmks(0, 0, bfr0, 0); mmks(0, 0, bfr0, 1);
        __builtin_amdgcn_s_setprio(0);
        BAR();
        // ---- ph6: (0,1) ----
        ldB(bfr1, &Bs[1][1][0], 0, s0);
        ldB(bfr1, &Bs[1][1][0], 1, s1);
        if constexpr (!LAST) stage(&As[1][0][0], Ag0, lda, kt + 192);  // t+3.A0
        __builtin_amdgcn_s_setprio(1);
        mmks(0, 1, bfr1, 0); mmks(0, 1, bfr1, 1);
        __builtin_amdgcn_s_setprio(0);
        BAR();
        // ---- ph7: (1,1) ----
        ldA(&As[1][1][0], 0, s0);
        ldA(&As[1][1][0], 1, s1);
        if constexpr (!LAST) stage(&Bs[1][0][0], Bg0, ldb, kt + 192);  // t+3.B0
        __builtin_amdgcn_s_setprio(1);
        mmks(1, 1, bfr1, 0); mmks(1, 1, bfr1, 1);
        __builtin_amdgcn_s_setprio(0);
        BAR();
        // ---- ph8: (1,0) — register-only MFMA, publish tile t+2 ----
        if constexpr (!LAST) stage(&Bs[1][1][0], Bg1, ldb, kt + 192);  // t+3.B1
        __builtin_amdgcn_s_setprio(1);
        mmks(1, 0, bfr0, 0); mmks(1, 0, bfr0, 1);
        __builtin_amdgcn_s_setprio(0);
        if constexpr (!LAST) {
            WAITV(6);
            __builtin_amdgcn_sched_barrier(0);
        }
        BAR();
    };

    const int nfull = (K >> 7) - 1;      // K % 128 == 0
    for (int i = 0; i < nfull; ++i) {
        iterbody(FalseT{});
        kt += 128;
    }
    iterbody(TrueT{});

    // epilogue: C/D layout col=lane&15, row=quad*4+reg; store order (mt,nt,r)
#pragma unroll
    for (int mt = 0; mt < 8; ++mt) {
        const int mq = mt >> 2, m4 = mt & 3;
#pragma unroll
        for (int nt = 0; nt < 4; ++nt) {
            const int nq = nt >> 1, n2 = nt & 1;
            const size_t col = bn0 + nq * 128 + wc * 32 + n2 * 16 + l16;
            const float bc = (CMODE == 0) ? bias[col] : 0.0f;
#pragma unroll
            for (int r = 0; r < 4; ++r) {
                const size_t row = bm0 + mq * 128 + wr * 64 + m4 * 16 + quad * 4 + r;
                float v = acc[mt][nt][r] * scale + bc;
                if (CMODE == 2) v = __expf(v);
                Cout[row * (size_t)ldc + col] = f2bf(v);
            }
        }
    }
}

// ---------------------------------------------------------------------------
// Fused cooperative kernel: prep | qkv | transpose | E | out | reduce,
// separated by grid.sync(). 256 blocks x 512 threads, 1 block/CU.
// ---------------------------------------------------------------------------
__global__ __launch_bounds__(512)
void fused(const float* __restrict__ x, const float* __restrict__ W1,
           const float* __restrict__ b1, const float* __restrict__ W2,
           const float* __restrict__ b2, const float* __restrict__ W3,
           const float* __restrict__ b3, float* __restrict__ out,
           char* __restrict__ wsb)
{
    __shared__ __align__(16) short As[2][2][128 * 64];  // 64 KiB
    __shared__ __align__(16) short Bs[2][2][128 * 64];  // 64 KiB

    // workspace layout (same as R12):
    short* vt   = (short*)wsb;                                      // 8 MB
    short* E    = (short*)(wsb + (size_t)8  * 1024 * 1024);         // 32 MB
    short* xb   = (short*)(wsb + (size_t)40 * 1024 * 1024);         // 8 MB
    short* Wb   = (short*)(wsb + (size_t)48 * 1024 * 1024);         // 6 MB
    float* bcat = (float*)(wsb + (size_t)54 * 1024 * 1024);         // 12 KB
    short* qkv  = (short*)(wsb + (size_t)54 * 1024 * 1024 + 16384); // 24 MB
    short* outp = (short*)(wsb + (size_t)40 * 1024 * 1024);         // 32 MB overlay

    const int bid = blockIdx.x;
    const int tid = threadIdx.x;
    cg::grid_group grid = cg::this_grid();

    // ---- phase 1: prep (casts + bias concat), grid-stride ----
    // 1835008 float4 items = 14 exact iterations of 256*512 threads.
#pragma unroll 1
    for (int it = 0; it < 14; ++it) {
        const int i = it * 131072 + bid * 512 + tid;
        const float* src; short* dst; int j;
        if (i < 1048576)      { src = x;  dst = xb;            j = i; }
        else if (i < 1310720) { src = W1; dst = Wb;            j = i - 1048576; }
        else if (i < 1572864) { src = W2; dst = Wb + 1048576;  j = i - 1310720; }
        else                  { src = W3; dst = Wb + 2097152;  j = i - 1572864; }
        const float4 f = ((const float4*)src)[j];
        short4 o;
        o.x = f2bf(f.x); o.y = f2bf(f.y); o.z = f2bf(f.z); o.w = f2bf(f.w);
        *(short4*)(dst + (j << 2)) = o;
    }
    {
        const int g = bid * 512 + tid;
        if (g < 3072)
            bcat[g] = (g < 1024) ? b1[g] : (g < 2048 ? b2[g - 1024] : b3[g - 2048]);
    }
    grid.sync();

    // ---- phase 2: qkv = x @ [W1;W2;W3]^T + bias (192 of 256 blocks) ----
    if (bid < 192) {
        gemm_body<0>(As, Bs, xb, 1024, Wb, 1024, bcat,
                     qkv, 3072, 1.0f, 1024, bid % 12, bid / 12, 0);
    }
    grid.sync();

    // ---- phase 3: vt[d][n] = qkv[n*3072+2048+d], 4 64x64 tiles/block ----
    {
        short (*sh)[64][72] = (short (*)[64][72])&As[0][0][0];  // 18 KiB
        const int half = tid >> 8;          // 2 concurrent tiles
        const int tt = tid & 255;
        const int r = tt >> 2, c = (tt & 3) << 4;
#pragma unroll 1
        for (int i2 = 0; i2 < 2; ++i2) {
            const int t = bid * 4 + i2 * 2 + half;          // < 1024
            const int n0 = (t & 63) * 64, d0 = (t >> 6) * 64;
            const short* src = qkv + (size_t)(n0 + r) * 3072 + 2048 + d0 + c;
            *(int4*)(&sh[half][r][c])     = *(const int4*)(src);
            *(int4*)(&sh[half][r][c + 8]) = *(const int4*)(src + 8);
            __syncthreads();
            short tmp[16];
#pragma unroll
            for (int j = 0; j < 16; j++) tmp[j] = sh[half][c + j][r];
            short* dst = vt + (size_t)(d0 + r) * 4096 + n0 + c;
            *(int4*)(dst)     = *(const int4*)(tmp);
            *(int4*)(dst + 8) = *(const int4*)(tmp + 8);
            __syncthreads();
        }
    }
    grid.sync();

    // ---- phase 4: E = exp((k q^T)/32), grid 16x16 ----
    gemm_body<2>(As, Bs, qkv + 1024, 3072, qkv, 3072, nullptr,
                 E, 4096, 0.03125f, 1024, bid & 15, bid >> 4, 0);
    grid.sync();

    // ---- phase 5: out partials = E @ vt^T, split-K=4, grid 4x16x4 ----
    {
        const int bz = bid >> 6;
        gemm_body<3>(As, Bs, E, 4096, vt, 4096, nullptr,
                     outp + (size_t)bz * 4194304, 1024, 1.0f, 1024,
                     bid & 3, (bid >> 2) & 15, bz * 1024);
    }
    grid.sync();

    // ---- phase 6: out = (sum_z partial_z) / rowsum(E), 16 rows/block ----
    {
        float* red = (float*)&As[0][0][0];
#pragma unroll 1
        for (int rr = 0; rr < 16; ++rr) {
            const int row = bid + rr * 256;
            // row-sum of E[row][4096]: 8 elems/thread over 512 threads
            const short* e = E + (size_t)row * 4096 + tid * 8;
            short sh8[8];
            *(int4*)sh8 = *(const int4*)(e);
            float s = 0.0f;
#pragma unroll
            for (int j = 0; j < 8; j++) s += bf2f(sh8[j]);
#pragma unroll
            for (int off = 32; off; off >>= 1) s += __shfl_down(s, off);
            if ((tid & 63) == 0) red[tid >> 6] = s;
            __syncthreads();
            const float inv = 1.0f / (red[0] + red[1] + red[2] + red[3] +
                                      red[4] + red[5] + red[6] + red[7]);
            // sum 4 bf16 partial rows, 2 cols/thread
            const size_t base = (size_t)row * 1024 + tid * 2;
            float a0 = 0.0f, a1 = 0.0f;
#pragma unroll
            for (int z = 0; z < 4; z++) {
                const int p = *(const int*)(outp + (size_t)z * 4194304 + base);
                a0 += bf2f((short)(p & 0xffff));
                a1 += bf2f((short)(((unsigned)p) >> 16));
            }
            float2 o2;
            o2.x = a0 * inv; o2.y = a1 * inv;
            *(float2*)(out + base) = o2;
            __syncthreads();   // red reused next iteration
        }
    }
}

extern "C" void kernel_launch(void* const* d_in, const int* in_sizes, int n_in,
                              void* d_out, int out_size, void* d_ws, size_t ws_size,
                              hipStream_t stream)
{
    const float* x  = (const float*)d_in[0];
    const float* W1 = (const float*)d_in[1];
    const float* b1 = (const float*)d_in[2];
    const float* W2 = (const float*)d_in[3];
    const float* b2 = (const float*)d_in[4];
    const float* W3 = (const float*)d_in[5];
    const float* b3 = (const float*)d_in[6];
    float* out = (float*)d_out;
    char* wsb = (char*)d_ws;

    void* args[] = { (void*)&x, (void*)&W1, (void*)&b1, (void*)&W2,
                     (void*)&b2, (void*)&W3, (void*)&b3, (void*)&out,
                     (void*)&wsb };
    hipLaunchCooperativeKernel((const void*)fused, dim3(256), dim3(512),
                               args, 0, stream);
}

// Round 11
// 214.833 us; speedup vs baseline: 1.8778x; 1.8778x over previous
//
#include <hip/hip_runtime.h>

// ---------------------------------------------------------------------------
// self_transformer: q=xW1^T+b1, k=xW2^T+b2, v=xW3^T+b3,
//                   attn=softmax((k q^T)/sqrt(D)), out=attn@v
// N=4096, D=1024. All matmuls via mfma_f32_16x16x32_bf16, fp32 accum.
// R18 = R12 (best measured: 212.5us) with the standalone transpose kernel
//       folded into the E-gemm LAUNCH as 64 trailing blocks:
//       grid (16,20); blockIdx.y>=16 -> transpose path (early return,
//       separate code, reuses As LDS), dispatched after the 256 gemm
//       blocks so they backfill CUs as gemm blocks finish. Saves one
//       launch + gap and hides the transpose's ~4us under the E tail.
//       R17's cooperative mega-fusion REVERTED (317us: I-cache thrash +
//       grid.sync tails). R13/R15/R16 rsum fusion REVERTED (net-negative).
//   gemm schedule (verbatim R12): 8 phases / 2 K-tiles per iteration;
//   reads in consume order (compiler per-use lgkmcnt); 1 stage (2 gld_lds)
//   per phase, rotation ph1:t+1.A1, ph2:t+2.A0, ph3:t+2.B0, ph4:t+2.B1,
//   ph5:t+2.A1, ph6:t+3.A0, ph7:t+3.B0, ph8:t+3.B1; vmcnt(6) only at
//   ph4/ph8 (publishes tile t+1 / t+2); 1 barrier per phase (post-MFMA);
//   last iteration peeled (vmcnt(0) only there). Epilogue store order
//   (mt,nt,r) — do NOT reorder (R13/R15: +7us on the out-gemm).
//   LDS half [128 rows][8 granules of 8 shorts], slot s of row r holds
//   global granule s^(r&7); read slot (ks*4+quad)^(l16&7) -> 0 bank
//   conflicts (measured R7-R13). Requires K % 128 == 0.
// ---------------------------------------------------------------------------

typedef short bf16x8 __attribute__((ext_vector_type(8)));  // 8 bf16 = 4 VGPRs
typedef float f32x4  __attribute__((ext_vector_type(4)));

struct FalseT { static constexpr bool value = false; };
struct TrueT  { static constexpr bool value = true;  };

__device__ __forceinline__ short f2bf(float f) {
    unsigned u = __builtin_bit_cast(unsigned, f);
    u += 0x7FFFu + ((u >> 16) & 1u);   // round-to-nearest-even
    return (short)(u >> 16);
}
__device__ __forceinline__ float bf2f(short s) {
    return __builtin_bit_cast(float, (unsigned)((unsigned short)s) << 16);
}

__device__ __forceinline__ void gld_lds16(const short* g, short* l) {
    __builtin_amdgcn_global_load_lds(
        (const __attribute__((address_space(1))) void*)g,
        (__attribute__((address_space(3))) void*)l, 16, 0, 0);
}

#define WAITV(n) asm volatile("s_waitcnt vmcnt(" #n ")" ::: "memory")
#define BAR()    __builtin_amdgcn_s_barrier()

// ---------------------------------------------------------------------------
// 256x256 BT GEMM, BK=64, 512 threads = 8 waves (2M x 4N), per-wave 128x64
// output spread across quadrant halves. C[a][b] = scale * sum A[a,i]*B[b,i].
// CMODE: 0 = bf16 + bias; 2 = bf16 exp() — and blocks with blockIdx.y>=16
//        run the folded V-transpose (tsrc=qkv base, tdst=vt) instead;
//        3 = bf16 at split-K offset z*zstride.
// ---------------------------------------------------------------------------
template<int CMODE>
__global__ __launch_bounds__(512)
void gemm256(const short* __restrict__ A, int lda,
             const short* __restrict__ B, int ldb,
             const float* __restrict__ bias,
             short* __restrict__ Cout, int ldc, float scale,
             int K, size_t zstride,
             const short* __restrict__ tsrc, short* __restrict__ tdst)
{
    __shared__ __align__(16) short As[2][2][128 * 64];  // [parity][mq-half]
    __shared__ __align__(16) short Bs[2][2][128 * 64];  // [parity][nq-half]

    const int tid  = threadIdx.x;

    // ---- folded transpose path (CMODE==2, trailing 64 blocks) ----
    // vt[d][n] = qkv[n*3072 + 2048 + d], 1024 64x64 tiles; 16 tiles/block,
    // 2 concurrent (512 threads = 2x the standalone kernel's 256).
    // Dispatched last (y-major linearization) -> backfills freed CUs.
    if constexpr (CMODE == 2) {
        if (blockIdx.y >= 16) {
            short (*sh)[64][72] = (short (*)[64][72])&As[0][0][0];  // 18 KiB
            const int tb = (blockIdx.y - 16) * 16 + blockIdx.x;     // 0..63
            const int half = tid >> 8;
            const int tt = tid & 255;
            const int r = tt >> 2, c = (tt & 3) << 4;
#pragma unroll 1
            for (int i = 0; i < 8; ++i) {
                const int t = tb * 16 + i * 2 + half;               // 0..1023
                const int n0 = (t & 63) * 64, d0 = (t >> 6) * 64;
                const short* src = tsrc + (size_t)(n0 + r) * 3072 + 2048 + d0 + c;
                *(int4*)(&sh[half][r][c])     = *(const int4*)(src);
                *(int4*)(&sh[half][r][c + 8]) = *(const int4*)(src + 8);
                __syncthreads();
                short tmp[16];
#pragma unroll
                for (int j = 0; j < 16; j++) tmp[j] = sh[half][c + j][r];
                short* dst = tdst + (size_t)(d0 + r) * 4096 + n0 + c;
                *(int4*)(dst)     = *(const int4*)(tmp);
                *(int4*)(dst + 8) = *(const int4*)(tmp + 8);
                __syncthreads();
            }
            return;
        }
    }

    const int lane = tid & 63;
    const int wave = tid >> 6;           // 0..7
    const int wr   = wave >> 2;          // 0..1
    const int wc   = wave & 3;           // 0..3
    const int quad = lane >> 4;
    const int l16  = lane & 15;
    const size_t bm0 = (size_t)blockIdx.y * 256;
    const size_t bn0 = (size_t)blockIdx.x * 256;
    const int koff = blockIdx.z * K;

    f32x4 acc[8][4] = {};

    // staging decode: stage call writes 16 rows (wave*16..+15) of one half;
    // lane l -> row +8*i+(l>>3), LDS slot (l&7), global granule (l&7)^(l>>3)
    const int srow  = lane >> 3;
    const int sgran = (lane & 7) ^ srow;
    const short* Ag0 = A + (bm0 + wave * 16 + srow) * (size_t)lda + koff + sgran * 8;
    const short* Ag1 = Ag0 + (size_t)128 * lda;
    const short* Bg0 = B + (bn0 + wave * 16 + srow) * (size_t)ldb + koff + sgran * 8;
    const short* Bg1 = Bg0 + (size_t)128 * ldb;

    // fragment read offsets within a [128][64] half
    const int s0   = ((quad ^ (l16 & 7)) << 3);         // ks=0 slot
    const int s1   = (((4 + quad) ^ (l16 & 7)) << 3);   // ks=1 slot
    const int rdA0 = (wr * 64 + l16) * 64;
    const int rdB0 = (wc * 32 + l16) * 64;

    auto stage = [&](short* half, const short* g, int ld, int kt) {
#pragma unroll
        for (int i = 0; i < 2; ++i)
            gld_lds16(g + (size_t)(i * 8) * ld + kt,
                      half + (wave * 16 + i * 8) * 64);
    };

    bf16x8 af[4][2], bfr0[2][2], bfr1[2][2];

    auto ldA = [&](const short* Ah, int ks, int soff) {
#pragma unroll
        for (int m4 = 0; m4 < 4; ++m4)
            af[m4][ks] = *(const bf16x8*)(Ah + rdA0 + m4 * 1024 + soff);
    };
    auto ldB = [&](bf16x8 (&bx)[2][2], const short* Bh, int ks, int soff) {
#pragma unroll
        for (int n2 = 0; n2 < 2; ++n2)
            bx[n2][ks] = *(const bf16x8*)(Bh + rdB0 + n2 * 1024 + soff);
    };
    auto mmks = [&](int mq, int nq, bf16x8 (&bx)[2][2], int ks) {
#pragma unroll
        for (int m4 = 0; m4 < 4; ++m4)
#pragma unroll
            for (int n2 = 0; n2 < 2; ++n2)
                acc[mq * 4 + m4][nq * 2 + n2] =
                    __builtin_amdgcn_mfma_f32_16x16x32_bf16(
                        af[m4][ks], bx[n2][ks],
                        acc[mq * 4 + m4][nq * 2 + n2], 0, 0, 0);
    };

    // prologue: tile0 all 4 halves (8 loads, retired by vmcnt(6)), then
    // tile1 {A0,B0,B1} (6 loads, stay in flight). tile1.A1 staged at ph1.
    stage(&As[0][0][0], Ag0, lda, 0);
    stage(&Bs[0][0][0], Bg0, ldb, 0);
    stage(&Bs[0][1][0], Bg1, ldb, 0);
    stage(&As[0][1][0], Ag1, lda, 0);
    stage(&As[1][0][0], Ag0, lda, 64);
    stage(&Bs[1][0][0], Bg0, ldb, 64);
    stage(&Bs[1][1][0], Bg1, ldb, 64);
    WAITV(6);
    BAR();
    __builtin_amdgcn_sched_barrier(0);

    int kt = 0;
    auto iterbody = [&](auto LASTC) {
        constexpr bool LAST = decltype(LASTC)::value;
        // ---- ph1: tile t, quadrant (0,0) ----
        ldB(bfr0, &Bs[0][0][0], 0, s0);
        ldA(&As[0][0][0], 0, s0);
        ldB(bfr0, &Bs[0][0][0], 1, s1);
        ldA(&As[0][0][0], 1, s1);
        stage(&As[1][1][0], Ag1, lda, kt + 64);        // t+1.A1
        __builtin_amdgcn_s_setprio(1);
        mmks(0, 0, bfr0, 0); mmks(0, 0, bfr0, 1);
        __builtin_amdgcn_s_setprio(0);
        BAR();
        // ---- ph2: (0,1) ----
        ldB(bfr1, &Bs[0][1][0], 0, s0);
        ldB(bfr1, &Bs[0][1][0], 1, s1);
        if constexpr (!LAST) stage(&As[0][0][0], Ag0, lda, kt + 128);  // t+2.A0
        __builtin_amdgcn_s_setprio(1);
        mmks(0, 1, bfr1, 0); mmks(0, 1, bfr1, 1);
        __builtin_amdgcn_s_setprio(0);
        BAR();
        // ---- ph3: (1,1) ----
        ldA(&As[0][1][0], 0, s0);
        ldA(&As[0][1][0], 1, s1);
        if constexpr (!LAST) stage(&Bs[0][0][0], Bg0, ldb, kt + 128);  // t+2.B0
        __builtin_amdgcn_s_setprio(1);
        mmks(1, 1, bfr1, 0); mmks(1, 1, bfr1, 1);
        __builtin_amdgcn_s_setprio(0);
        BAR();
        // ---- ph4: (1,0) — register-only MFMA, publish tile t+1 ----
        if constexpr (!LAST) stage(&Bs[0][1][0], Bg1, ldb, kt + 128);  // t+2.B1
        __builtin_amdgcn_s_setprio(1);
        mmks(1, 0, bfr0, 0); mmks(1, 0, bfr0, 1);
        __builtin_amdgcn_s_setprio(0);
        if constexpr (LAST) { WAITV(0); } else { WAITV(6); }
        __builtin_amdgcn_sched_barrier(0);
        BAR();
        // ---- ph5: tile t+1, quadrant (0,0) ----
        ldB(bfr0, &Bs[1][0][0], 0, s0);
        ldA(&As[1][0][0], 0, s0);
        ldB(bfr0, &Bs[1][0][0], 1, s1);
        ldA(&As[1][0][0], 1, s1);
        if constexpr (!LAST) stage(&As[0][1][0], Ag1, lda, kt + 128);  // t+2.A1
        __builtin_amdgcn_s_setprio(1);
        mmks(0, 0, bfr0, 0); mmks(0, 0, bfr0, 1);
        __builtin_amdgcn_s_setprio(0);
        BAR();
        // ---- ph6: (0,1) ----
        ldB(bfr1, &Bs[1][1][0], 0, s0);
        ldB(bfr1, &Bs[1][1][0], 1, s1);
        if constexpr (!LAST) stage(&As[1][0][0], Ag0, lda, kt + 192);  // t+3.A0
        __builtin_amdgcn_s_setprio(1);
        mmks(0, 1, bfr1, 0); mmks(0, 1, bfr1, 1);
        __builtin_amdgcn_s_setprio(0);
        BAR();
        // ---- ph7: (1,1) ----
        ldA(&As[1][1][0], 0, s0);
        ldA(&As[1][1][0], 1, s1);
        if constexpr (!LAST) stage(&Bs[1][0][0], Bg0, ldb, kt + 192);  // t+3.B0
        __builtin_amdgcn_s_setprio(1);
        mmks(1, 1, bfr1, 0); mmks(1, 1, bfr1, 1);
        __builtin_amdgcn_s_setprio(0);
        BAR();
        // ---- ph8: (1,0) — register-only MFMA, publish tile t+2 ----
        if constexpr (!LAST) stage(&Bs[1][1][0], Bg1, ldb, kt + 192);  // t+3.B1
        __builtin_amdgcn_s_setprio(1);
        mmks(1, 0, bfr0, 0); mmks(1, 0, bfr0, 1);
        __builtin_amdgcn_s_setprio(0);
        if constexpr (!LAST) {
            WAITV(6);
            __builtin_amdgcn_sched_barrier(0);
        }
        BAR();
    };

    const int nfull = (K >> 7) - 1;      // K % 128 == 0
    for (int i = 0; i < nfull; ++i) {
        iterbody(FalseT{});
        kt += 128;
    }
    iterbody(TrueT{});

    // epilogue: C/D layout col=lane&15, row=quad*4+reg; store order (mt,nt,r)
    short* Cs = Cout + ((CMODE == 3) ? (size_t)blockIdx.z * zstride : 0);
#pragma unroll
    for (int mt = 0; mt < 8; ++mt) {
        const int mq = mt >> 2, m4 = mt & 3;
#pragma unroll
        for (int nt = 0; nt < 4; ++nt) {
            const int nq = nt >> 1, n2 = nt & 1;
            const size_t col = bn0 + nq * 128 + wc * 32 + n2 * 16 + l16;
            const float bc = (CMODE == 0) ? bias[col] : 0.0f;
#pragma unroll
            for (int r = 0; r < 4; ++r) {
                const size_t row = bm0 + mq * 128 + wr * 64 + m4 * 16 + quad * 4 + r;
                float v = acc[mt][nt][r] * scale + bc;
                if (CMODE == 2) v = __expf(v);
                Cs[row * (size_t)ldc + col] = f2bf(v);
            }
        }
    }
}

// One block per output row n: rsum = sum(E[n,:]); out[n,:] =
// (sum_z partial_z[n,:]) / rsum. Partials are bf16, 4 splits of 4096x1024.
__global__ __launch_bounds__(256)
void reduce4div(const short* __restrict__ E, const short* __restrict__ outp,
                float* __restrict__ out)
{
    const int row = blockIdx.x;
    const int t = threadIdx.x;
    const int wave = t >> 6, lane = t & 63;

    // row-sum of E[row][4096], 16 elems/thread
    const short* e = E + (size_t)row * 4096 + (t << 4);
    short sh[16];
    *(int4*)(sh)     = *(const int4*)(e);
    *(int4*)(sh + 8) = *(const int4*)(e + 8);
    float s = 0.0f;
#pragma unroll
    for (int i = 0; i < 16; i++) s += bf2f(sh[i]);
#pragma unroll
    for (int off = 32; off; off >>= 1) s += __shfl_down(s, off);
    __shared__ float red[4];
    if (lane == 0) red[wave] = s;
    __syncthreads();
    const float inv = 1.0f / (red[0] + red[1] + red[2] + red[3]);

    // sum 4 bf16 partial rows, 4 cols/thread
    const size_t base = (size_t)row * 1024 + (t << 2);
    float a[4] = {0.0f, 0.0f, 0.0f, 0.0f};
#pragma unroll
    for (int z = 0; z < 4; z++) {
        short4 p = *(const short4*)(outp + z * (size_t)4096 * 1024 + base);
        a[0] += bf2f(p.x); a[1] += bf2f(p.y);
        a[2] += bf2f(p.z); a[3] += bf2f(p.w);
    }
    float4 o;
    o.x = a[0] * inv; o.y = a[1] * inv; o.z = a[2] * inv; o.w = a[3] * inv;
    *(float4*)(out + base) = o;
}

// single prep: x->xb (1M float4), W1|W2|W3 -> Wb (3x256K float4), bias cat
// Wb sub-matrix offsets are in SHORT ELEMENTS (1048576 elems per W).
__global__ __launch_bounds__(256)
void prep(const float* __restrict__ x, const float* __restrict__ W1,
          const float* __restrict__ W2, const float* __restrict__ W3,
          const float* __restrict__ b1, const float* __restrict__ b2,
          const float* __restrict__ b3,
          short* __restrict__ xb, short* __restrict__ Wb,
          float* __restrict__ bcat)
{
    const int i = blockIdx.x * 256 + threadIdx.x;
    const int NX = 1048576;           // 4096*1024/4
    const int NW = 262144;            // 1024*1024/4
    if (i < NX + 3 * NW) {
        const float* src; short* dst; int j;
        if (i < NX)               { src = x;  dst = xb; j = i; }
        else if (i < NX + NW)     { src = W1; dst = Wb; j = i - NX; }
        else if (i < NX + 2 * NW) { src = W2; dst = Wb + 1048576; j = i - NX - NW; }
        else                      { src = W3; dst = Wb + 2097152; j = i - NX - 2 * NW; }
        const float4 f = ((const float4*)src)[j];
        short4 o;
        o.x = f2bf(f.x); o.y = f2bf(f.y); o.z = f2bf(f.z); o.w = f2bf(f.w);
        *(short4*)(dst + (j << 2)) = o;
    } else {
        const int j = i - (NX + 3 * NW);
        if (j < 3072)
            bcat[j] = (j < 1024) ? b1[j] : (j < 2048 ? b2[j - 1024] : b3[j - 2048]);
    }
}

extern "C" void kernel_launch(void* const* d_in, const int* in_sizes, int n_in,
                              void* d_out, int out_size, void* d_ws, size_t ws_size,
                              hipStream_t stream)
{
    const float* x  = (const float*)d_in[0];
    const float* W1 = (const float*)d_in[1];
    const float* b1 = (const float*)d_in[2];
    const float* W2 = (const float*)d_in[3];
    const float* b2 = (const float*)d_in[4];
    const float* W3 = (const float*)d_in[5];
    const float* b3 = (const float*)d_in[6];
    float* out = (float*)d_out;

    const int N = 4096, D = 1024;

    // workspace (peak 79 MB):
    //   vt   [0, 8M)            live: E+transpose launch .. out-gemm
    //   E    [8M, 40M)          live: E launch .. reduce
    //   xb   [40M, 48M)  \
    //   Wb   [48M, 54M)   }     dead after E launch
    //   bcat [54M, +12K)  }
    //   qkv  [54M+16K, ~78M)   /
    //   outp [40M, 72M)         bf16 partials, overlays dead region
    char* wsb = (char*)d_ws;
    short* vt   = (short*)wsb;                               // 1024x4096 bf16
    short* E    = (short*)(wsb + (size_t)8  * 1024 * 1024);  // 4096x4096 bf16
    short* xb   = (short*)(wsb + (size_t)40 * 1024 * 1024);  // 4096x1024 bf16
    short* Wb   = (short*)(wsb + (size_t)48 * 1024 * 1024);  // 3072x1024 bf16
    float* bcat = (float*)(wsb + (size_t)54 * 1024 * 1024);  // 3072 fp32
    short* qkv  = (short*)(wsb + (size_t)54 * 1024 * 1024 + 16384); // 4096x3072
    short* outp = (short*)(wsb + (size_t)40 * 1024 * 1024);  // 4x 4096x1024 bf16

    // 1) prep: casts + bias concat (one launch)
    prep<<<(1048576 + 3 * 262144 + 3072 + 255) / 256, 256, 0, stream>>>(
        x, W1, W2, W3, b1, b2, b3, xb, Wb, bcat);

    // 2) qkv = x @ [W1;W2;W3]^T + bias  (256x256, grid (12,16)=192)
    dim3 gqkv(3 * D / 256, N / 256);
    gemm256<0><<<gqkv, 512, 0, stream>>>(xb, D, Wb, D, bcat,
                                         qkv, 3 * D, 1.0f, D, 0,
                                         nullptr, nullptr);

    // 3+4) E = exp((k q^T)/32) bf16, grid (16,16) gemm blocks + 64 trailing
    //      transpose blocks (y=16..19) writing vt[d][n] = v[n][d].
    dim3 gs(N / 256, N / 256 + 4);
    gemm256<2><<<gs, 512, 0, stream>>>(qkv + D, 3 * D, qkv, 3 * D,
                                       nullptr, E, N, 0.03125f, D, 0,
                                       qkv, vt);

    // 5) out partials = E @ vt^T, split-K=4, bf16 (grid (4,16,4)=256)
    dim3 go(D / 256, N / 256, 4);
    gemm256<3><<<go, 512, 0, stream>>>(E, N, vt, N, nullptr,
                                       outp, D, 1.0f, N / 4,
                                       (size_t)N * D, nullptr, nullptr);

    // 6) out = (sum_z partial_z) / rowsum(E)
    reduce4div<<<N, 256, 0, stream>>>(E, outp, out);
}